// Round 2
// baseline (614.338 us; speedup 1.0000x reference)
//
#include <hip/hip_runtime.h>
#include <hip/hip_bf16.h>
#include <stdint.h>

typedef unsigned short ushort_t;
typedef __attribute__((ext_vector_type(8))) short bf16x8;
typedef __attribute__((ext_vector_type(4))) float f32x4;

#define EPSQ 1e-5f

// exact for small integers (codes); round-nearest-even for general floats
__device__ __forceinline__ unsigned f2bf(float f) {
  union { float f; unsigned u; } x; x.f = f;
  unsigned r = x.u + 0x7fffu + ((x.u >> 16) & 1u);
  return r >> 16;
}

__device__ __forceinline__ void async_copy16(const ushort_t* g, ushort_t* l) {
  __builtin_amdgcn_global_load_lds(
      (const __attribute__((address_space(1))) unsigned int*)g,
      (__attribute__((address_space(3))) unsigned int*)l,
      16, 0, 0);
}

// ---------------- W absmean reduction (double accumulation) ----------------
__global__ __launch_bounds__(256) void abssum_kernel(const float4* __restrict__ W,
                                                     double* __restrict__ sum, int n4) {
  double acc = 0.0;
  int stride = gridDim.x * blockDim.x;
  for (int v = blockIdx.x * blockDim.x + threadIdx.x; v < n4; v += stride) {
    float4 p = W[v];
    acc += (double)fabsf(p.x) + (double)fabsf(p.y) +
           (double)fabsf(p.z) + (double)fabsf(p.w);
  }
  for (int off = 32; off > 0; off >>= 1) acc += __shfl_down(acc, off);
  if ((threadIdx.x & 63) == 0) atomicAdd(sum, acc);
}

// ---------------- finalize scalars + A_eff ----------------
// scalf layout: [0..1]=double sum|W|, [2]=mw (dequant), [3]=sw=1/mw (quant)
__global__ void finalize_kernel(const float* __restrict__ A_raw, float* __restrict__ scalf,
                                float* __restrict__ a_eff, int D, double inv_cnt) {
  int i = blockIdx.x * blockDim.x + threadIdx.x;
  if (i < D) a_eff[i] = 0.99f * tanhf(A_raw[i]);
  if (i == 0) {
    double s = *(const double*)scalf;
    float mw = fmaxf((float)(s * inv_cnt), EPSQ);  // clip(mean|W|, EPS)
    scalf[2] = mw;
    scalf[3] = 1.0f / mw;
  }
}

// ---------------- ternary quantize W -> CODES {-1,0,1} as bf16 ----------------
__global__ __launch_bounds__(256) void quantw_kernel(const float4* __restrict__ W,
                                                     uint4* __restrict__ Wq,
                                                     const float* __restrict__ scalf, int n8) {
  float sw = scalf[3];
  int stride = gridDim.x * blockDim.x;
  for (int v = blockIdx.x * blockDim.x + threadIdx.x; v < n8; v += stride) {
    float4 a = W[2 * v], b = W[2 * v + 1];
    float c[8] = {a.x, a.y, a.z, a.w, b.x, b.y, b.z, b.w};
    unsigned o[8];
#pragma unroll
    for (int i = 0; i < 8; ++i) {
      float q = fminf(fmaxf(rintf(c[i] * sw), -1.f), 1.f);
      o[i] = f2bf(q);  // exact: {-1,0,1}
    }
    uint4 po;
    po.x = o[0] | (o[1] << 16); po.y = o[2] | (o[3] << 16);
    po.z = o[4] | (o[5] << 16); po.w = o[6] | (o[7] << 16);
    Wq[v] = po;
  }
}

// ---------------- per-token int8 quant of e -> CODES [-127,127] as bf16 -------
// one block per token row; K == 2048 == 256 threads * 8 elems
__global__ __launch_bounds__(256) void quante_kernel(const float* __restrict__ E,
                                                     ushort_t* __restrict__ Eq,
                                                     float* __restrict__ rowscale, int K) {
  __shared__ float red[4];
  int row = blockIdx.x;
  int tid = threadIdx.x;
  const float4* src = (const float4*)(E + (size_t)row * K);
  float4 a = src[2 * tid], b = src[2 * tid + 1];
  float v[8] = {a.x, a.y, a.z, a.w, b.x, b.y, b.z, b.w};
  float amax = 0.f;
#pragma unroll
  for (int i = 0; i < 8; ++i) amax = fmaxf(amax, fabsf(v[i]));
  for (int off = 32; off > 0; off >>= 1) amax = fmaxf(amax, __shfl_down(amax, off));
  if ((tid & 63) == 0) red[tid >> 6] = amax;
  __syncthreads();
  amax = fmaxf(fmaxf(red[0], red[1]), fmaxf(red[2], red[3]));
  float clipped = fmaxf(amax, EPSQ);
  float scale = 127.0f / clipped;   // matches jax: 127/clip(max|x|,EPS)
  unsigned o[8];
#pragma unroll
  for (int i = 0; i < 8; ++i) {
    float q = fminf(fmaxf(rintf(v[i] * scale), -128.f), 127.f);
    o[i] = f2bf(q);  // exact: integer codes
  }
  uint4 po;
  po.x = o[0] | (o[1] << 16); po.y = o[2] | (o[3] << 16);
  po.z = o[4] | (o[5] << 16); po.w = o[6] | (o[7] << 16);
  ((uint4*)(Eq + (size_t)row * K))[tid] = po;
  if (tid == 0) rowscale[row] = clipped / 127.0f;  // == 1/scale to 2^-24
}

// ---------------- 128x128x32 bf16 MFMA GEMM on codes + fused epilogue --------
// Cint[m,n] = sum_k eq[m,k]*wq[n,k]  (EXACT: |partial| < 2^24 in fp32)
// out = a_eff[n]*h + Cint*rowscale[m]*mw + bo   (fp32)
__global__ __launch_bounds__(256) void gemm_kernel(
    const ushort_t* __restrict__ Eq, const ushort_t* __restrict__ Wq,
    const float* __restrict__ h, const float* __restrict__ bo,
    const float* __restrict__ a_eff, const float* __restrict__ rowscale,
    const float* __restrict__ scalf, float* __restrict__ out,
    int M, int N, int K) {
  __shared__ ushort_t As[128 * 32];
  __shared__ ushort_t Bs[128 * 32];

  int tid = threadIdx.x;
  int lane = tid & 63;
  int wave = tid >> 6;
  int wm = wave >> 1, wn = wave & 1;
  int m0 = blockIdx.y * 128;
  int n0 = blockIdx.x * 128;

  // staging: thread t covers (row = t>>2, 8-elem chunk = t&3); lds byte off = 16*t
  // (wave-uniform base + lane*16 — required layout for global_load_lds)
  int sr = tid >> 2;
  int sc = (tid & 3) * 8;

  const ushort_t* ga0 = Eq + (size_t)(m0 + sr) * K + sc;
  const ushort_t* ga1 = ga0 + (size_t)64 * K;
  const ushort_t* gb0 = Wq + (size_t)(n0 + sr) * K + sc;
  const ushort_t* gb1 = gb0 + (size_t)64 * K;
  ushort_t* la0 = As + sr * 32 + sc;
  ushort_t* la1 = la0 + 64 * 32;
  ushort_t* lb0 = Bs + sr * 32 + sc;
  ushort_t* lb1 = lb0 + 64 * 32;

  f32x4 acc[4][4] = {};

  int lm = lane & 15;
  int kg = (lane >> 4) * 8;
  const ushort_t* arow = As + (wm * 64 + lm) * 32 + kg;
  const ushort_t* brow = Bs + (wn * 64 + lm) * 32 + kg;

  int ktiles = K / 32;
  for (int kt = 0; kt < ktiles; ++kt) {
    async_copy16(ga0, la0);
    async_copy16(ga1, la1);
    async_copy16(gb0, lb0);
    async_copy16(gb1, lb1);
    ga0 += 32; ga1 += 32; gb0 += 32; gb1 += 32;
    __syncthreads();  // vmcnt(0) drain covers global_load_lds
    bf16x8 af[4], bg[4];
#pragma unroll
    for (int i = 0; i < 4; ++i) af[i] = *(const bf16x8*)(arow + i * 16 * 32);
#pragma unroll
    for (int j = 0; j < 4; ++j) bg[j] = *(const bf16x8*)(brow + j * 16 * 32);
#pragma unroll
    for (int i = 0; i < 4; ++i)
#pragma unroll
      for (int j = 0; j < 4; ++j)
        acc[i][j] = __builtin_amdgcn_mfma_f32_16x16x32_bf16(af[i], bg[j], acc[i][j], 0, 0, 0);
    __syncthreads();
  }

  // epilogue: C/D layout col=lane&15 (n), row=(lane>>4)*4+reg (m)  [m89/m91]
  float mw = scalf[2];
  int r4 = (lane >> 4) * 4;
  float aeffj[4];
#pragma unroll
  for (int j = 0; j < 4; ++j) aeffj[j] = a_eff[n0 + wn * 64 + j * 16 + lm];
#pragma unroll
  for (int i = 0; i < 4; ++i) {
    int mb = m0 + wm * 64 + i * 16 + r4;
#pragma unroll
    for (int r = 0; r < 4; ++r) {
      size_t ro = (size_t)(mb + r) * N;
      float sm = rowscale[mb + r] * mw;
#pragma unroll
      for (int j = 0; j < 4; ++j) {
        int n = n0 + wn * 64 + j * 16 + lm;
        float val = fmaf(acc[i][j][r], sm, fmaf(aeffj[j], h[ro + n], bo[ro + n]));
        out[ro + n] = val;
      }
    }
  }
}

extern "C" void kernel_launch(void* const* d_in, const int* in_sizes, int n_in,
                              void* d_out, int out_size, void* d_ws, size_t ws_size,
                              hipStream_t stream) {
  const float* h_p   = (const float*)d_in[0];
  const float* e_p   = (const float*)d_in[1];
  const float* bo_p  = (const float*)d_in[2];
  const float* A_raw = (const float*)d_in[3];
  const float* W_p   = (const float*)d_in[4];
  float* out = (float*)d_out;

  int D = in_sizes[3];        // 2048
  int M = in_sizes[0] / D;    // 16384
  int N = D, K = D;

  char* ws = (char*)d_ws;
  float* scalf     = (float*)ws;                       // [0..1]=dbl sum, [2]=mw, [3]=sw
  float* a_eff     = (float*)(ws + 4096);              // D floats
  float* rowscale  = (float*)(ws + 65536);             // M floats (64 KB)
  ushort_t* Wq     = (ushort_t*)(ws + 131072);         // N*K bf16 codes (8 MB)
  ushort_t* Eq     = (ushort_t*)(ws + 131072 + (size_t)N * K * 2);  // M*K bf16 codes (64 MB)

  hipMemsetAsync(d_ws, 0, 64, stream);
  int nW = N * K;
  abssum_kernel<<<256, 256, 0, stream>>>((const float4*)W_p, (double*)scalf, nW / 4);
  finalize_kernel<<<(D + 255) / 256, 256, 0, stream>>>(A_raw, scalf, a_eff, D,
                                                       1.0 / (double)nW);
  quantw_kernel<<<256, 256, 0, stream>>>((const float4*)W_p, (uint4*)Wq, scalf, nW / 8);
  quante_kernel<<<M, 256, 0, stream>>>(e_p, Eq, rowscale, K);
  dim3 grid(N / 128, M / 128);
  gemm_kernel<<<grid, 256, 0, stream>>>(Eq, Wq, h_p, bo_p, a_eff, rowscale, scalf, out,
                                        M, N, K);
}